// Round 1
// baseline (234.398 us; speedup 1.0000x reference)
//
#include <hip/hip_runtime.h>
#include <hip/hip_bf16.h>
#include <math.h>

#define Hdim 768
#define Idim 3072
#define Tn   1024
#define En   8
#define CAP  256   // per-expert bucket capacity (12 sigma above mean count of 128)
#define LD1  72    // Bs stride (shorts), BK=64: 144 B = 4 banks (mod 32)
#define LD2  136   // Bs stride (shorts), BK=128: 272 B = 4 banks (mod 32)

using v4f     = __attribute__((ext_vector_type(4))) float;
using short8  = __attribute__((ext_vector_type(8))) short;
using short4v = __attribute__((ext_vector_type(4))) short;

__device__ inline unsigned short f2bf(float f) {
    unsigned u = __float_as_uint(f);
    u += 0x7fffu + ((u >> 16) & 1u);   // RNE
    return (unsigned short)(u >> 16);
}
__device__ inline short4v pack4(float4 v) {
    return short4v{ (short)f2bf(v.x), (short)f2bf(v.y), (short)f2bf(v.z), (short)f2bf(v.w) };
}
__device__ __forceinline__ void gl2lds16(const unsigned short* g, unsigned short* l) {
    __builtin_amdgcn_global_load_lds(
        (const __attribute__((address_space(1))) void*)g,
        (__attribute__((address_space(3))) void*)l, 16, 0, 0);
}

// ---------------- gate: logits -> sel + per-block partial stats (no atomics) ----------------
__global__ __launch_bounds__(256) void gate_kernel(
    const float* __restrict__ x, const float* __restrict__ gw, const float* __restrict__ gb,
    float* __restrict__ psum, float* __restrict__ psumsq,
    int* __restrict__ sel, int* __restrict__ gcur)
{
    __shared__ float gws[8 * 772];
    __shared__ float lg[8][8];
    int tid = threadIdx.x;
    long t0 = (long)blockIdx.x * 8;
    if (blockIdx.x == 0 && tid < En) gcur[tid] = 0;   // gather runs after all gate blocks
    for (int i = tid; i < 8 * 768; i += 256) gws[(i / 768) * 772 + (i % 768)] = gw[i];
    __syncthreads();

    int tok = tid >> 5, e = (tid >> 2) & 7, qr = tid & 3;
    const float4* xp = (const float4*)(x + (t0 + tok) * Hdim) + qr * 48;
    const float4* gp = (const float4*)(gws + e * 772) + qr * 48;
    float a0 = 0.f, a1 = 0.f;
#pragma unroll 8
    for (int i = 0; i < 48; i += 2) {
        float4 xa = xp[i], ga = gp[i], xc = xp[i + 1], gc = gp[i + 1];
        a0 += xa.x * ga.x + xa.y * ga.y + xa.z * ga.z + xa.w * ga.w;
        a1 += xc.x * gc.x + xc.y * gc.y + xc.z * gc.z + xc.w * gc.w;
    }
    float acc = a0 + a1;
    acc += __shfl_xor(acc, 1);
    acc += __shfl_xor(acc, 2);
    if (qr == 0) lg[tok][e] = acc + gb[e];
    __syncthreads();

    if (tid < 8) {
        float best = lg[tid][0]; int bi = 0;
        for (int j = 1; j < 8; j++) { float v = lg[tid][j]; if (v > best) { best = v; bi = j; } }
        sel[t0 + tid] = bi;
    } else if (tid < 16) {
        int e2 = tid - 8;
        float s = 0.f, ss = 0.f;
        for (int t2 = 0; t2 < 8; t2++) { float v = lg[t2][e2]; s += v; ss += v * v; }
        psum[blockIdx.x * 8 + e2]   = s;
        psumsq[blockIdx.x * 8 + e2] = ss;
    }
}

// ---------------- gather: ticketed perm + x->bf16 bucket copy + lb finalize ----------------
__global__ __launch_bounds__(256) void gather_kernel(
    const float* __restrict__ x, const int* __restrict__ sel,
    const float* __restrict__ psum, const float* __restrict__ psumsq,
    int* __restrict__ gcur, int* __restrict__ perm,
    unsigned short* __restrict__ xb, float* __restrict__ out_lb)
{
    int tid = threadIdx.x;
    // block 0, wave 0: reduce 128x8 partial stats -> lb_loss (deterministic order)
    if (blockIdx.x == 0 && tid < 64) {
        int e = tid & 7, c0 = (tid >> 3) * 16;
        float s = 0.f, ss = 0.f;
        for (int b = c0; b < c0 + 16; b++) { s += psum[b * 8 + e]; ss += psumsq[b * 8 + e]; }
        s  += __shfl_xor(s, 8);  s  += __shfl_xor(s, 16);  s  += __shfl_xor(s, 32);
        ss += __shfl_xor(ss, 8); ss += __shfl_xor(ss, 16); ss += __shfl_xor(ss, 32);
        if (tid < 8) {
            float mean = s * (1.0f / 1024.0f);
            float var  = (ss - s * mean) * (1.0f / 1023.0f);   // ddof=1
            float r = var / (mean * mean + 1e-8f);
            r += __shfl_xor(r, 1); r += __shfl_xor(r, 2); r += __shfl_xor(r, 4);
            if (tid == 0) out_lb[0] = 0.01f * r * 0.125f;
        }
    }
    // ticketed bucket placement: one wave per token, 4 tokens per block
    int t = blockIdx.x * 4 + (tid >> 6);
    int lane = tid & 63;
    int e = sel[t];
    int pos = 0;
    if (lane == 0) pos = atomicAdd(&gcur[e], 1);
    pos = __shfl(pos, 0);
    if (pos < CAP) {
        int slot = (e << 8) + pos;
        if (lane == 0) perm[slot] = t;
        const float4* src = (const float4*)(x + (long)t * Hdim);
        unsigned short* dst = xb + (long)slot * Hdim;
#pragma unroll
        for (int i = 0; i < 3; i++) {
            int c = lane + 64 * i;
            *(short4v*)(dst + c * 4) = pack4(src[c]);
        }
    }
}

// ---------------- GEMM1: hmid = gelu(xb @ w1^T + b1) -> bf16 ----------------
// tile 64(M) x 32(N), BK=64, grid (96, 4, 8)
__global__ __launch_bounds__(256) void gemm1_kernel(
    const unsigned short* __restrict__ xb, const float* __restrict__ w1, const float* __restrict__ b1,
    const int* __restrict__ count, unsigned short* __restrict__ hmid)
{
    int e = blockIdx.z;
    int nloc = count[e]; if (nloc > CAP) nloc = CAP;
    int m0 = blockIdx.y << 6;
    if (m0 >= nloc) return;
    int n0 = blockIdx.x << 5;
    int off = e << 8;

    __shared__ __align__(16) unsigned short As[64 * 64];    // 8 KB, XOR-swizzled chunks
    __shared__ __align__(16) unsigned short Bs[32 * LD1];   // 4.5 KB

    int tid = threadIdx.x;
    int lane = tid & 63, wave = tid >> 6;
    int quad = lane >> 4, l16 = lane & 15;
    int wm = wave << 4;                                     // wave tile 16(M) x 32(N)

    // A staging: 512 16B-chunks, 2 per thread, lane-contiguous LDS dest, swizzled global src
    const unsigned short* aG[2];
    unsigned short* aL[2];
#pragma unroll
    for (int i = 0; i < 2; i++) {
        int p = (wave * 2 + i) * 64 + lane;
        int row = p >> 3;
        int kc = (p & 7) ^ (row & 7);
        int m = m0 + row; int mm = m < nloc ? m : nloc - 1;
        aG[i] = xb + (long)(off + mm) * Hdim + kc * 8;
        aL[i] = (unsigned short*)As + p * 8;
    }
    // B: 32 rows x 64 fp32
    int kq = tid & 15, rb = tid >> 4;
    const float* bp0 = w1 + ((long)e * Idim + n0 + rb) * Hdim + kq * 4;
    const float* bp1 = bp0 + (long)16 * Hdim;

    v4f acc[2];
    acc[0] = (v4f){0.f, 0.f, 0.f, 0.f};
    acc[1] = (v4f){0.f, 0.f, 0.f, 0.f};

    float4 nb0 = *(const float4*)bp0;
    float4 nb1 = *(const float4*)bp1;

    for (int kb = 0; kb < Hdim; kb += 64) {
        __syncthreads();
#pragma unroll
        for (int i = 0; i < 2; i++) gl2lds16(aG[i] + kb, aL[i]);
        *(short4v*)(Bs + rb * LD1 + kq * 4)        = pack4(nb0);
        *(short4v*)(Bs + (rb + 16) * LD1 + kq * 4) = pack4(nb1);
        __syncthreads();
        if (kb + 64 < Hdim) {
            nb0 = *(const float4*)(bp0 + kb + 64);
            nb1 = *(const float4*)(bp1 + kb + 64);
        }
#pragma unroll
        for (int s = 0; s < 2; s++) {
            int r = wm + l16;
            short8 af = *(const short8*)(As + r * 64 + (((s * 4 + quad) ^ (r & 7)) * 8));
            short8 bf2[2];
#pragma unroll
            for (int j = 0; j < 2; j++)
                bf2[j] = *(const short8*)(Bs + (j * 16 + l16) * LD1 + s * 32 + quad * 8);
#pragma unroll
            for (int j = 0; j < 2; j++)
                acc[j] = __builtin_amdgcn_mfma_f32_16x16x32_bf16(af, bf2[j], acc[j], 0, 0, 0);
        }
    }

    int mr = wm + quad * 4;
#pragma unroll
    for (int r = 0; r < 4; r++) {
        int m = m0 + mr + r;
        if (m >= nloc) continue;
        long slot = off + m;
#pragma unroll
        for (int j = 0; j < 2; j++) {
            int n = n0 + j * 16 + l16;
            float v = acc[j][r] + b1[e * Idim + n];
            float g = 0.5f * v * (1.0f + erff(v * 0.70710678118654752f));
            hmid[slot * Idim + n] = f2bf(g);
        }
    }
}

// ---------------- GEMM2: out[t] = hmid @ w2^T + b2 (full K, no atomics) ----------------
// tile 64(M) x 32(N), BK=128, K=3072 in one pass, grid (24, 4, 8)
__global__ __launch_bounds__(256) void gemm2_kernel(
    const unsigned short* __restrict__ hmid, const float* __restrict__ w2,
    const float* __restrict__ b2,
    const int* __restrict__ count, const int* __restrict__ perm,
    float* __restrict__ out)
{
    int e = blockIdx.z;
    int nloc = count[e]; if (nloc > CAP) nloc = CAP;
    int m0 = blockIdx.y << 6;
    if (m0 >= nloc) return;
    int n0 = blockIdx.x << 5;           // 24 * 32 = 768
    int off = e << 8;

    __shared__ __align__(16) unsigned short As[64 * 128];   // 16 KB, XOR-swizzled chunks
    __shared__ __align__(16) unsigned short Bs[32 * LD2];   //  8.7 KB

    int tid = threadIdx.x;
    int lane = tid & 63, wave = tid >> 6;
    int quad = lane >> 4, l16 = lane & 15;
    int wm = wave << 4;                                     // wave tile 16 x 32

    // A staging: 1024 chunks, 4 per thread
    const unsigned short* aG[4];
    unsigned short* aL[4];
#pragma unroll
    for (int i = 0; i < 4; i++) {
        int p = (wave * 4 + i) * 64 + lane;
        int row = p >> 4;
        int kc = (p & 15) ^ (row & 15);
        int m = m0 + row; int mm = m < nloc ? m : nloc - 1;
        aG[i] = hmid + (long)(off + mm) * Idim + kc * 8;
        aL[i] = (unsigned short*)As + p * 8;
    }
    // B: 32 rows x 128 fp32
    int kq5 = tid & 31, rb8 = tid >> 5;
    const float* bp[4];
#pragma unroll
    for (int s = 0; s < 4; s++)
        bp[s] = w2 + ((long)e * Hdim + n0 + rb8 + 8 * s) * Idim + kq5 * 4;

    v4f acc[2];
    acc[0] = (v4f){0.f, 0.f, 0.f, 0.f};
    acc[1] = (v4f){0.f, 0.f, 0.f, 0.f};

    float4 nb[4];
#pragma unroll
    for (int s = 0; s < 4; s++) nb[s] = *(const float4*)bp[s];

    for (int kb = 0; kb < Idim; kb += 128) {
        __syncthreads();
#pragma unroll
        for (int i = 0; i < 4; i++) gl2lds16(aG[i] + kb, aL[i]);
#pragma unroll
        for (int s = 0; s < 4; s++)
            *(short4v*)(Bs + (rb8 + 8 * s) * LD2 + kq5 * 4) = pack4(nb[s]);
        __syncthreads();
        if (kb + 128 < Idim) {
#pragma unroll
            for (int s = 0; s < 4; s++) nb[s] = *(const float4*)(bp[s] + kb + 128);
        }
#pragma unroll
        for (int s = 0; s < 4; s++) {
            int r = wm + l16;
            short8 af = *(const short8*)(As + r * 128 + (((s * 4 + quad) ^ (r & 15)) * 8));
            short8 bf2[2];
#pragma unroll
            for (int j = 0; j < 2; j++)
                bf2[j] = *(const short8*)(Bs + (j * 16 + l16) * LD2 + s * 32 + quad * 8);
#pragma unroll
            for (int j = 0; j < 2; j++)
                acc[j] = __builtin_amdgcn_mfma_f32_16x16x32_bf16(af, bf2[j], acc[j], 0, 0, 0);
        }
    }

    int mr = wm + quad * 4;
#pragma unroll
    for (int r = 0; r < 4; r++) {
        int m = m0 + mr + r;
        if (m >= nloc) continue;
        int t = perm[off + m];
#pragma unroll
        for (int j = 0; j < 2; j++) {
            int n = n0 + j * 16 + l16;
            out[(long)t * Hdim + n] = acc[j][r] + b2[e * Hdim + n];
        }
    }
}

extern "C" void kernel_launch(void* const* d_in, const int* in_sizes, int n_in,
                              void* d_out, int out_size, void* d_ws, size_t ws_size,
                              hipStream_t stream)
{
    const float* x  = (const float*)d_in[0];
    const float* gw = (const float*)d_in[1];
    const float* gb = (const float*)d_in[2];
    const float* w1 = (const float*)d_in[3];
    const float* b1 = (const float*)d_in[4];
    const float* w2 = (const float*)d_in[5];
    const float* b2 = (const float*)d_in[6];
    float* out = (float*)d_out;

    int*   gcur   = (int*)d_ws;                           // 8 ints (ticket counters == counts)
    int*   sel    = (int*)((char*)d_ws + 128);            // 1024 ints
    float* psum   = (float*)((char*)d_ws + 4352);         // 128x8 partial sums
    float* psumsq = (float*)((char*)d_ws + 8448);         // 128x8 partial sumsq
    int*   perm   = (int*)((char*)d_ws + 12544);          // 2048 ints (8 buckets x CAP)
    unsigned short* xb   = (unsigned short*)((char*)d_ws + 32768);       // 2048 x 768 bf16
    unsigned short* hmid = (unsigned short*)((char*)d_ws + (1u << 22));  // 2048 x 3072 bf16

    gate_kernel  <<<128, 256, 0, stream>>>(x, gw, gb, psum, psumsq, sel, gcur);
    gather_kernel<<<256, 256, 0, stream>>>(x, sel, psum, psumsq, gcur, perm, xb,
                                           out + (long)Tn * Hdim);
    gemm1_kernel <<<dim3(96, 4, 8), 256, 0, stream>>>(xb, w1, b1, gcur, hmid);
    gemm2_kernel <<<dim3(24, 4, 8), 256, 0, stream>>>(hmid, w2, b2, gcur, perm, out);
}